// Round 1
// baseline (65.748 us; speedup 1.0000x reference)
//
#include <hip/hip_runtime.h>

#define NCLS 80

__device__ __forceinline__ float softplus_f(float x) {
    return fmaxf(x, 0.f) + log1pf(expf(-fabsf(x)));
}

// One block per (scale s, batch b): reduce softplus over the 3 obj channels.
__global__ void obj_reduce_kernel(const float* __restrict__ p0,
                                  const float* __restrict__ p1,
                                  const float* __restrict__ p2,
                                  float* __restrict__ full) {
    int blk = blockIdx.x;          // 0..95
    int s = blk >> 5;              // scale
    int b = blk & 31;              // batch
    const float* p; int G;
    if (s == 0)      { p = p0; G = 13; }
    else if (s == 1) { p = p1; G = 26; }
    else             { p = p2; G = 52; }
    int GG = G * G;
    int n = 3 * GG;
    float sum = 0.f;
    for (int i = threadIdx.x; i < n; i += blockDim.x) {
        int a   = i / GG;
        int pos = i - a * GG;
        float x = p[((size_t)(b * 255 + a * 85 + 4)) * GG + pos];
        sum += softplus_f(x);
    }
    // wave (64-lane) reduce, then cross-wave via LDS
    for (int off = 32; off > 0; off >>= 1) sum += __shfl_down(sum, off);
    __shared__ float part[4];
    int wave = threadIdx.x >> 6;
    if ((threadIdx.x & 63) == 0) part[wave] = sum;
    __syncthreads();
    if (threadIdx.x == 0) {
        full[blk] = part[0] + part[1] + part[2] + part[3];
    }
}

// One block (1 wave) per (s,b); lanes 0..19 each handle one target.
__global__ void target_kernel(const float* __restrict__ p0,
                              const float* __restrict__ p1,
                              const float* __restrict__ p2,
                              const float* __restrict__ targets,
                              const float* __restrict__ anchors,
                              const float* __restrict__ full,
                              float* __restrict__ acc) {
    int blk = blockIdx.x;
    int s = blk >> 5, b = blk & 31;
    const float* p; int G; float stride;
    if (s == 0)      { p = p0; G = 13; stride = 32.f; }
    else if (s == 1) { p = p1; G = 26; stride = 16.f; }
    else             { p = p2; G = 52; stride = 8.f; }
    int GG = G * G;
    float contrib = 0.f;
    int t = threadIdx.x;
    if (t < 20) {
        const float* tg = targets + (b * 20 + t) * 5;
        float tc_f = tg[0];
        float x1 = tg[1], y1 = tg[2], x2 = tg[3], y2 = tg[4];
        float inv_stride = 1.f / stride;
        float gx = x1 * inv_stride, gy = y1 * inv_stride;
        float gw = (x2 - x1) * inv_stride, gh = (y2 - y1) * inv_stride;
        float fgi = floorf(gx), fgj = floorf(gy);
        bool valid = (fgi >= 0.f) && (fgi < (float)G) && (fgj >= 0.f) && (fgj < (float)G);
        int gi = (int)fminf(fmaxf(fgi, 0.f), (float)(G - 1));
        int gj = (int)fminf(fmaxf(fgj, 0.f), (float)(G - 1));
        // best anchor by IoU on (w,h) only; first-max semantics like jnp.argmax
        float best_iou = -1.f; float best_aw = 0.f, best_ah = 0.f; int best = 0;
        for (int a = 0; a < 3; ++a) {
            float aw = anchors[(s * 3 + a) * 2 + 0] * inv_stride;
            float ah = anchors[(s * 3 + a) * 2 + 1] * inv_stride;
            float inter = fminf(gw, aw) * fminf(gh, ah);
            float uni   = gw * gh + aw * ah - inter;
            float iou   = inter / (uni + 1e-16f);
            if (iou > best_iou) { best_iou = iou; best = a; best_aw = aw; best_ah = ah; }
        }
        const float* base = p + ((size_t)(b * 255 + best * 85)) * GG + gj * G + gi;
        float px = base[0], py = base[(size_t)GG];
        px = 1.f / (1.f + expf(-px));
        py = 1.f / (1.f + expf(-py));
        float pw   = base[2 * (size_t)GG];
        float ph   = base[3 * (size_t)GG];
        float pobj = base[4 * (size_t)GG];
        float gtx = gx - (float)gi, gty = gy - (float)gj;
        float gtw = logf(fmaxf(gw, 1e-16f) / (best_aw + 1e-16f));
        float gth = logf(fmaxf(gh, 1e-16f) / (best_ah + 1e-16f));
        float box = (px - gtx) * (px - gtx) + (py - gty) * (py - gty)
                  + (pw - gtw) * (pw - gtw) + (ph - gth) * (ph - gth);
        int tc = (int)tc_f;
        float cls = 0.f;
        for (int c = 0; c < NCLS; ++c) {
            float v = base[(5 + c) * (size_t)GG];
            cls += softplus_f(v);
            if (c == tc) cls -= v;
        }
        if (valid) {
            contrib = 5.f * box
                    + softplus_f(-pobj)
                    + cls
                    + 50.f * (full[blk] - softplus_f(pobj) + 0.69314718056f);
        }
    }
    for (int off = 32; off > 0; off >>= 1) contrib += __shfl_down(contrib, off);
    if (threadIdx.x == 0) atomicAdd(acc, contrib);
}

__global__ void finalize_kernel(const float* __restrict__ acc, float* __restrict__ out) {
    out[0] = acc[0] * (1.f / 32.f);
}

extern "C" void kernel_launch(void* const* d_in, const int* in_sizes, int n_in,
                              void* d_out, int out_size, void* d_ws, size_t ws_size,
                              hipStream_t stream) {
    const float* p0      = (const float*)d_in[0];
    const float* p1      = (const float*)d_in[1];
    const float* p2      = (const float*)d_in[2];
    const float* targets = (const float*)d_in[3];
    const float* anchors = (const float*)d_in[4];

    float* ws   = (float*)d_ws;
    float* acc  = ws;        // ws[0]
    float* full = ws + 16;   // ws[16..111]: full[s*32+b]

    hipMemsetAsync(acc, 0, sizeof(float), stream);
    obj_reduce_kernel<<<96, 256, 0, stream>>>(p0, p1, p2, full);
    target_kernel<<<96, 64, 0, stream>>>(p0, p1, p2, targets, anchors, full, acc);
    finalize_kernel<<<1, 1, 0, stream>>>(acc, (float*)d_out);
}

// Round 2
// 27.770 us; speedup vs baseline: 2.3676x; 2.3676x over previous
//
#include <hip/hip_runtime.h>

#define NCLS 80
#define LOG2F_ 0.69314718056f

__device__ __forceinline__ float softplus_f(float x) {
    return fmaxf(x, 0.f) + log1pf(expf(-fabsf(x)));
}

// One block per (scale s, batch b, anchor a): reduce softplus(obj) over G*G,
// atomicAdd into full[s*32+b].
__global__ void obj_reduce_kernel(const float* __restrict__ p0,
                                  const float* __restrict__ p1,
                                  const float* __restrict__ p2,
                                  float* __restrict__ full) {
    int blk = blockIdx.x;          // 0..287
    int s   = blk / 96;
    int rem = blk - s * 96;
    int b   = rem / 3;
    int a   = rem - b * 3;
    const float* p; int G;
    if (s == 0)      { p = p0; G = 13; }
    else if (s == 1) { p = p1; G = 26; }
    else             { p = p2; G = 52; }
    int GG = G * G;
    const float* src = p + ((size_t)(b * 255 + a * 85 + 4)) * GG;
    float sum = 0.f;
    for (int i = threadIdx.x; i < GG; i += blockDim.x)
        sum += softplus_f(src[i]);
    for (int off = 32; off > 0; off >>= 1) sum += __shfl_down(sum, off);
    __shared__ float part[4];
    int wave = threadIdx.x >> 6;
    if ((threadIdx.x & 63) == 0) part[wave] = sum;
    __syncthreads();
    if (threadIdx.x == 0)
        atomicAdd(&full[s * 32 + b], part[0] + part[1] + part[2] + part[3]);
}

// One WAVE per (s,b,t): lane l loads channel l (and 64+l for l<21) at the
// target's grid cell; per-lane loss terms; wave reduce; block LDS reduce;
// one atomicAdd per block.
__global__ void target_kernel(const float* __restrict__ p0,
                              const float* __restrict__ p1,
                              const float* __restrict__ p2,
                              const float* __restrict__ targets,
                              const float* __restrict__ anchors,
                              const float* __restrict__ full,
                              float* __restrict__ acc) {
    int wave = threadIdx.x >> 6;
    int lane = threadIdx.x & 63;
    int gw   = blockIdx.x * 4 + wave;      // 0..1919
    int sb   = gw / 20;                    // 0..95
    int t    = gw - sb * 20;
    int s    = sb >> 5, b = sb & 31;

    const float* p; int G; float inv_stride;
    if (s == 0)      { p = p0; G = 13; inv_stride = 1.f / 32.f; }
    else if (s == 1) { p = p1; G = 26; inv_stride = 1.f / 16.f; }
    else             { p = p2; G = 52; inv_stride = 1.f / 8.f;  }
    int GG = G * G;

    // All lanes compute identical target-level values (broadcast loads).
    const float* tg = targets + (b * 20 + t) * 5;
    float tc_f = tg[0];
    float x1 = tg[1], y1 = tg[2], x2 = tg[3], y2 = tg[4];
    float gx = x1 * inv_stride, gy = y1 * inv_stride;
    float gw_ = (x2 - x1) * inv_stride, gh_ = (y2 - y1) * inv_stride;
    float fgi = floorf(gx), fgj = floorf(gy);
    bool valid = (fgi >= 0.f) && (fgi < (float)G) && (fgj >= 0.f) && (fgj < (float)G);
    float vm = valid ? 1.f : 0.f;
    int gi = (int)fminf(fmaxf(fgi, 0.f), (float)(G - 1));
    int gj = (int)fminf(fmaxf(fgj, 0.f), (float)(G - 1));

    // Best anchor (first-max semantics, strict >)
    float best_iou = -1.f, best_aw = 0.f, best_ah = 0.f; int best = 0;
    for (int a = 0; a < 3; ++a) {
        float aw = anchors[(s * 3 + a) * 2 + 0] * inv_stride;
        float ah = anchors[(s * 3 + a) * 2 + 1] * inv_stride;
        float inter = fminf(gw_, aw) * fminf(gh_, ah);
        float uni   = gw_ * gh_ + aw * ah - inter;
        float iou   = inter / (uni + 1e-16f);
        if (iou > best_iou) { best_iou = iou; best = a; best_aw = aw; best_ah = ah; }
    }

    float gtx = gx - (float)gi, gty = gy - (float)gj;
    float gtw = logf(fmaxf(gw_, 1e-16f) / (best_aw + 1e-16f));
    float gth = logf(fmaxf(gh_, 1e-16f) / (best_ah + 1e-16f));
    int   tc  = (int)tc_f;

    const float* base = p + ((size_t)(b * 255 + best * 85)) * GG + gj * G + gi;

    // Lane l handles channel l; lanes 0..20 also handle channel 64+l.
    float v0 = base[(size_t)lane * GG];
    float v1 = (lane < 21) ? base[(size_t)(64 + lane) * GG] : 0.f;

    float term;
    int c = lane;
    if (c == 0) {
        float px = 1.f / (1.f + expf(-v0));
        term = 5.f * (px - gtx) * (px - gtx);
    } else if (c == 1) {
        float py = 1.f / (1.f + expf(-v0));
        term = 5.f * (py - gty) * (py - gty);
    } else if (c == 2) {
        term = 5.f * (v0 - gtw) * (v0 - gtw);
    } else if (c == 3) {
        term = 5.f * (v0 - gth) * (v0 - gth);
    } else if (c == 4) {
        term = softplus_f(-v0) - 50.f * softplus_f(v0);
    } else {
        term = softplus_f(v0) - ((c - 5 == tc) ? v0 : 0.f);
    }
    if (lane < 21) {
        int c1 = 64 + lane;                 // 64..84 -> classes 59..79
        term += softplus_f(v1) - ((c1 - 5 == tc) ? v1 : 0.f);
    }

    for (int off = 32; off > 0; off >>= 1) term += __shfl_down(term, off);

    __shared__ float part[4];
    if (lane == 0)
        part[wave] = vm * (term + 50.f * (full[sb] + LOG2F_));
    __syncthreads();
    if (threadIdx.x == 0)
        atomicAdd(acc, part[0] + part[1] + part[2] + part[3]);
}

__global__ void finalize_kernel(const float* __restrict__ acc, float* __restrict__ out) {
    out[0] = acc[0] * (1.f / 32.f);
}

extern "C" void kernel_launch(void* const* d_in, const int* in_sizes, int n_in,
                              void* d_out, int out_size, void* d_ws, size_t ws_size,
                              hipStream_t stream) {
    const float* p0      = (const float*)d_in[0];
    const float* p1      = (const float*)d_in[1];
    const float* p2      = (const float*)d_in[2];
    const float* targets = (const float*)d_in[3];
    const float* anchors = (const float*)d_in[4];

    float* ws   = (float*)d_ws;
    float* acc  = ws;        // ws[0]
    float* full = ws + 16;   // ws[16..111]: full[s*32+b]

    hipMemsetAsync(ws, 0, 128 * sizeof(float), stream);
    obj_reduce_kernel<<<288, 256, 0, stream>>>(p0, p1, p2, full);
    target_kernel<<<480, 256, 0, stream>>>(p0, p1, p2, targets, anchors, full, acc);
    finalize_kernel<<<1, 1, 0, stream>>>(acc, (float*)d_out);
}

// Round 3
// 13.497 us; speedup vs baseline: 4.8711x; 2.0574x over previous
//
#include <hip/hip_runtime.h>

#define LOG2F_ 0.69314718056f

// ws layout (floats): [0..287] obj partials (blk = sb*3 + a)
//                     [288..767] target loss partials (tb = 0..479)
//                     [768..1247] target nv partials  (tb = 0..479)
#define OP_OFF 0
#define TP_OFF 288
#define NP_OFF 768

__device__ __forceinline__ float softplus_f(float x) {
    return fmaxf(x, 0.f) + log1pf(expf(-fabsf(x)));
}

// Fused kernel: blocks [0,288) reduce softplus(obj) per (sb, anchor);
// blocks [288,768) handle 4 targets each (1 wave per target).
__global__ void yolo_main_kernel(const float* __restrict__ p0,
                                 const float* __restrict__ p1,
                                 const float* __restrict__ p2,
                                 const float* __restrict__ targets,
                                 const float* __restrict__ anchors,
                                 float* __restrict__ ws) {
    int blk  = blockIdx.x;
    int wave = threadIdx.x >> 6;
    int lane = threadIdx.x & 63;
    __shared__ float partl[4];
    __shared__ float partv[4];

    if (blk < 288) {
        // ---- obj reduction: blk = sb*3 + a, sb = s*32+b ----
        int sb = blk / 3;
        int a  = blk - sb * 3;
        int s  = sb >> 5, b = sb & 31;
        const float* p; int G;
        if (s == 0)      { p = p0; G = 13; }
        else if (s == 1) { p = p1; G = 26; }
        else             { p = p2; G = 52; }
        int GG = G * G;
        const float* src = p + ((size_t)(b * 255 + a * 85 + 4)) * GG;
        float sum = 0.f;
        for (int i = threadIdx.x; i < GG; i += 256)
            sum += softplus_f(src[i]);
        for (int off = 32; off > 0; off >>= 1) sum += __shfl_down(sum, off);
        if (lane == 0) partl[wave] = sum;
        __syncthreads();
        if (threadIdx.x == 0)
            ws[OP_OFF + blk] = partl[0] + partl[1] + partl[2] + partl[3];
    } else {
        // ---- target blocks: tb in [0,480), wave handles one (sb,t) ----
        int tb = blk - 288;
        int gw = tb * 4 + wave;            // 0..1919, all 4 within one sb
        int sb = gw / 20;
        int t  = gw - sb * 20;
        int s  = sb >> 5, b = sb & 31;

        const float* p; int G; float inv_stride;
        if (s == 0)      { p = p0; G = 13; inv_stride = 1.f / 32.f; }
        else if (s == 1) { p = p1; G = 26; inv_stride = 1.f / 16.f; }
        else             { p = p2; G = 52; inv_stride = 1.f / 8.f;  }
        int GG = G * G;

        const float* tg = targets + (b * 20 + t) * 5;
        float tc_f = tg[0];
        float x1 = tg[1], y1 = tg[2], x2 = tg[3], y2 = tg[4];
        float gx = x1 * inv_stride, gy = y1 * inv_stride;
        float gw_ = (x2 - x1) * inv_stride, gh_ = (y2 - y1) * inv_stride;
        float fgi = floorf(gx), fgj = floorf(gy);
        bool valid = (fgi >= 0.f) && (fgi < (float)G) && (fgj >= 0.f) && (fgj < (float)G);
        float vm = valid ? 1.f : 0.f;
        int gi = (int)fminf(fmaxf(fgi, 0.f), (float)(G - 1));
        int gj = (int)fminf(fmaxf(fgj, 0.f), (float)(G - 1));

        // best anchor, first-max (strict >) semantics
        float best_iou = -1.f, best_aw = 0.f, best_ah = 0.f; int best = 0;
        for (int a = 0; a < 3; ++a) {
            float aw = anchors[(s * 3 + a) * 2 + 0] * inv_stride;
            float ah = anchors[(s * 3 + a) * 2 + 1] * inv_stride;
            float inter = fminf(gw_, aw) * fminf(gh_, ah);
            float uni   = gw_ * gh_ + aw * ah - inter;
            float iou   = inter / (uni + 1e-16f);
            if (iou > best_iou) { best_iou = iou; best = a; best_aw = aw; best_ah = ah; }
        }

        float gtx = gx - (float)gi, gty = gy - (float)gj;
        float gtw = logf(fmaxf(gw_, 1e-16f) / (best_aw + 1e-16f));
        float gth = logf(fmaxf(gh_, 1e-16f) / (best_ah + 1e-16f));
        int   tc  = (int)tc_f;

        const float* base = p + ((size_t)(b * 255 + best * 85)) * GG + gj * G + gi;

        float v0 = base[(size_t)lane * GG];
        float v1 = (lane < 21) ? base[(size_t)(64 + lane) * GG] : 0.f;

        float term;
        int c = lane;
        if (c == 0) {
            float px = 1.f / (1.f + expf(-v0));
            term = 5.f * (px - gtx) * (px - gtx);
        } else if (c == 1) {
            float py = 1.f / (1.f + expf(-v0));
            term = 5.f * (py - gty) * (py - gty);
        } else if (c == 2) {
            term = 5.f * (v0 - gtw) * (v0 - gtw);
        } else if (c == 3) {
            term = 5.f * (v0 - gth) * (v0 - gth);
        } else if (c == 4) {
            term = softplus_f(-v0) - 50.f * softplus_f(v0);
        } else {
            term = softplus_f(v0) - ((c - 5 == tc) ? v0 : 0.f);
        }
        if (lane < 21) {
            int c1 = 64 + lane;
            term += softplus_f(v1) - ((c1 - 5 == tc) ? v1 : 0.f);
        }

        for (int off = 32; off > 0; off >>= 1) term += __shfl_down(term, off);

        if (lane == 0) {
            partl[wave] = vm * (term + 50.f * LOG2F_);
            partv[wave] = vm;
        }
        __syncthreads();
        if (threadIdx.x == 0) {
            ws[TP_OFF + tb] = partl[0] + partl[1] + partl[2] + partl[3];
            ws[NP_OFF + tb] = partv[0] + partv[1] + partv[2] + partv[3];
        }
    }
}

// Single-block reduce: Σ tp + 50 · Σ_sb nv[sb]·full[sb], then /32.
__global__ void finalize_kernel(const float* __restrict__ ws, float* __restrict__ out) {
    __shared__ float red[256];
    int tid = threadIdx.x;
    float v = 0.f;
    for (int i = tid; i < 480; i += 256) v += ws[TP_OFF + i];
    if (tid < 96) {
        float nv = 0.f;
        #pragma unroll
        for (int k = 0; k < 5; ++k) nv += ws[NP_OFF + tid * 5 + k];
        float full = ws[OP_OFF + tid * 3] + ws[OP_OFF + tid * 3 + 1] + ws[OP_OFF + tid * 3 + 2];
        v += 50.f * nv * full;
    }
    red[tid] = v;
    __syncthreads();
    for (int off = 128; off > 0; off >>= 1) {
        if (tid < off) red[tid] += red[tid + off];
        __syncthreads();
    }
    if (tid == 0) out[0] = red[0] * (1.f / 32.f);
}

extern "C" void kernel_launch(void* const* d_in, const int* in_sizes, int n_in,
                              void* d_out, int out_size, void* d_ws, size_t ws_size,
                              hipStream_t stream) {
    const float* p0      = (const float*)d_in[0];
    const float* p1      = (const float*)d_in[1];
    const float* p2      = (const float*)d_in[2];
    const float* targets = (const float*)d_in[3];
    const float* anchors = (const float*)d_in[4];
    float* ws = (float*)d_ws;

    yolo_main_kernel<<<768, 256, 0, stream>>>(p0, p1, p2, targets, anchors, ws);
    finalize_kernel<<<1, 256, 0, stream>>>(ws, (float*)d_out);
}